// Round 1
// baseline (1013.995 us; speedup 1.0000x reference)
//
#include <hip/hip_runtime.h>
#include <cstdint>
#include <cstddef>

#define NEG_SLOPE 0.2f
#define HC 512     // H*C
#define NH 4       // heads

__device__ inline float lrelu(float z) { return z > 0.f ? z : NEG_SLOPE * z; }

// ---------------------------------------------------------------------------
// Detect whether edge_index is int64 (odd int32 words all zero) or int32.
__global__ void detect_kernel(const int* __restrict__ ei, int E, int* __restrict__ flag) {
    __shared__ int nz;
    if (threadIdx.x == 0) nz = 0;
    __syncthreads();
    int lim = E < 256 ? E : 256;
    if (threadIdx.x < lim) {
        if (ei[2 * threadIdx.x + 1] != 0) atomicOr(&nz, 1);
    }
    __syncthreads();
    if (threadIdx.x == 0) *flag = (nz == 0) ? 1 : 0;   // 1 -> int64 layout
}

__device__ inline int edge_read(const int* ei, int is64, size_t idx) {
    return is64 ? ei[2 * idx] : ei[idx];
}

// ---------------------------------------------------------------------------
// Simple fp32 tiled GEMM: C[M,Nc] = A[M,K] @ B[K,Nc] (+ bias[Nc] if non-null)
// BM=BN=64, BK=16, 256 threads, 4x4 per thread.
__global__ __launch_bounds__(256) void gemm_kernel(
        const float* __restrict__ A, const float* __restrict__ B,
        const float* __restrict__ bias, float* __restrict__ C,
        int M, int K, int Nc) {
    __shared__ float As[64][17];                    // [m][k], padded
    __shared__ __align__(16) float Bs[16][64];      // [k][n]
    int tid = threadIdx.x;
    int bm = blockIdx.y * 64;
    int bn = blockIdx.x * 64;
    int tx = tid & 15, ty = tid >> 4;
    float acc[4][4] = {};

    for (int k0 = 0; k0 < K; k0 += 16) {
        {
            int j = tid & 15, i0 = tid >> 4;
            #pragma unroll
            for (int r = 0; r < 4; ++r) {
                int m = i0 + r * 16;
                int gm = bm + m;
                As[m][j] = (gm < M) ? A[(size_t)gm * K + k0 + j] : 0.f;
            }
        }
        {
            int c = tid & 63, r0 = tid >> 6;
            #pragma unroll
            for (int r = 0; r < 4; ++r) {
                int kk = r0 + r * 4;
                Bs[kk][c] = B[(size_t)(k0 + kk) * Nc + bn + c];
            }
        }
        __syncthreads();
        #pragma unroll
        for (int k = 0; k < 16; ++k) {
            float a0 = As[ty * 4 + 0][k];
            float a1 = As[ty * 4 + 1][k];
            float a2 = As[ty * 4 + 2][k];
            float a3 = As[ty * 4 + 3][k];
            float4 bv = *reinterpret_cast<const float4*>(&Bs[k][tx * 4]);
            acc[0][0] += a0 * bv.x; acc[0][1] += a0 * bv.y; acc[0][2] += a0 * bv.z; acc[0][3] += a0 * bv.w;
            acc[1][0] += a1 * bv.x; acc[1][1] += a1 * bv.y; acc[1][2] += a1 * bv.z; acc[1][3] += a1 * bv.w;
            acc[2][0] += a2 * bv.x; acc[2][1] += a2 * bv.y; acc[2][2] += a2 * bv.z; acc[2][3] += a2 * bv.w;
            acc[3][0] += a3 * bv.x; acc[3][1] += a3 * bv.y; acc[3][2] += a3 * bv.z; acc[3][3] += a3 * bv.w;
        }
        __syncthreads();
    }
    #pragma unroll
    for (int i = 0; i < 4; ++i) {
        int gm = bm + ty * 4 + i;
        if (gm >= M) continue;
        #pragma unroll
        for (int j = 0; j < 4; ++j) {
            int gn = bn + tx * 4 + j;
            float v = acc[i][j];
            if (bias) v += bias[gn];
            C[(size_t)gm * Nc + gn] = v;
        }
    }
}

// ---------------------------------------------------------------------------
// Per-node attention logits: a_src[n,h] = dot(x[n,h,:], att_src[h,:]), same dst
__global__ __launch_bounds__(256) void attdot_kernel(
        const float* __restrict__ x, const float* __restrict__ att_s,
        const float* __restrict__ att_d, float* __restrict__ a_src,
        float* __restrict__ a_dst, int N) {
    int n = blockIdx.x, t = threadIdx.x;
    size_t row = (size_t)n * HC;
    float x0 = x[row + t], x1 = x[row + 256 + t];
    float s0 = x0 * att_s[t], s1 = x1 * att_s[256 + t];
    float d0 = x0 * att_d[t], d1 = x1 * att_d[256 + t];
    #pragma unroll
    for (int o = 32; o > 0; o >>= 1) {
        s0 += __shfl_xor(s0, o); s1 += __shfl_xor(s1, o);
        d0 += __shfl_xor(d0, o); d1 += __shfl_xor(d1, o);
    }
    __shared__ float sS[4][2], sD[4][2];
    int w = t >> 6, lane = t & 63;
    if (lane == 0) {
        sS[w >> 1][w & 1] = s0;  sS[2 + (w >> 1)][w & 1] = s1;
        sD[w >> 1][w & 1] = d0;  sD[2 + (w >> 1)][w & 1] = d1;
    }
    __syncthreads();
    if (t < 4) {
        a_src[(size_t)n * 4 + t] = sS[t][0] + sS[t][1];
        a_dst[(size_t)n * 4 + t] = sD[t][0] + sD[t][1];
    }
}

// ---------------------------------------------------------------------------
__global__ __launch_bounds__(256) void edge_stats_kernel(
        const int* __restrict__ ei, const float* __restrict__ ew,
        const int* __restrict__ flag, int* __restrict__ cnt,
        float* __restrict__ wsum, int E) {
    int e = blockIdx.x * 256 + threadIdx.x;
    if (e >= E) return;
    int is64 = *flag;
    int d = edge_read(ei, is64, (size_t)E + e);
    atomicAdd(&cnt[d], 1);
    atomicAdd(&wsum[d], ew[e]);
}

// ---------------------------------------------------------------------------
// Single-block scan: offsets = exclusive_prefix(cnt); ea_mean = wsum/max(cnt,1)
// Also computes s_h = dot(W_edge[h,:], att_edge[h,:]).
__global__ __launch_bounds__(1024) void scan_kernel(
        const int* __restrict__ cnt, const float* __restrict__ wsum,
        int* __restrict__ offsets, float* __restrict__ ea_mean,
        const float* __restrict__ W_edge, const float* __restrict__ att_edge,
        float* __restrict__ sh, int N) {
    __shared__ int sbuf[1024];
    __shared__ int s_running;
    int t = threadIdx.x;
    if (t < NH) {
        float s = 0.f;
        for (int c = 0; c < 128; ++c) s += W_edge[t * 128 + c] * att_edge[t * 128 + c];
        sh[t] = s;
    }
    if (t == 0) s_running = 0;
    __syncthreads();
    for (int base = 0; base < N; base += 1024) {
        int idx = base + t;
        int v = (idx < N) ? cnt[idx] : 0;
        if (idx < N) ea_mean[idx] = wsum[idx] / fmaxf((float)v, 1.f);
        sbuf[t] = v;
        __syncthreads();
        for (int o = 1; o < 1024; o <<= 1) {
            int u = (t >= o) ? sbuf[t - o] : 0;
            __syncthreads();
            sbuf[t] += u;
            __syncthreads();
        }
        if (idx < N) offsets[idx] = s_running + sbuf[t] - v;
        int tot = sbuf[1023];
        __syncthreads();
        if (t == 0) s_running += tot;
        __syncthreads();
    }
    if (t == 0) offsets[N] = s_running;
}

// ---------------------------------------------------------------------------
__global__ __launch_bounds__(256) void fill_kernel(
        const int* __restrict__ ei, const int* __restrict__ flag,
        const int* __restrict__ offsets, int* __restrict__ fill,
        int* __restrict__ csr, int E) {
    int e = blockIdx.x * 256 + threadIdx.x;
    if (e >= E) return;
    int is64 = *flag;
    int d = edge_read(ei, is64, (size_t)E + e);
    int pos = offsets[d] + atomicAdd(&fill[d], 1);
    csr[pos] = e;
}

// ---------------------------------------------------------------------------
// One block per destination node: softmax denom + weighted gather of x[src].
__global__ __launch_bounds__(256) void agg_kernel(
        const float* __restrict__ x, const float* __restrict__ a_src,
        const float* __restrict__ a_dst, const float* __restrict__ ea_mean,
        const float* __restrict__ sh, const float* __restrict__ ew,
        const int* __restrict__ ei, const int* __restrict__ flag,
        const int* __restrict__ csr, const int* __restrict__ offsets,
        const float* __restrict__ bias, float* __restrict__ agg, int N, int E) {
    int n = blockIdx.x;
    int t = threadIdx.x;
    int is64 = *flag;
    int beg = offsets[n], end = offsets[n + 1];

    __shared__ float s_alpha[256][4];
    __shared__ int   s_srcv[256];
    __shared__ float4 s_red[256];

    float ad0 = a_dst[(size_t)n * 4 + 0], ad1 = a_dst[(size_t)n * 4 + 1];
    float ad2 = a_dst[(size_t)n * 4 + 2], ad3 = a_dst[(size_t)n * 4 + 3];
    float sh0 = sh[0], sh1 = sh[1], sh2 = sh[2], sh3 = sh[3];
    float eam = ea_mean[n];
    float es0 = __expf(lrelu(a_src[(size_t)n * 4 + 0] + ad0 + eam * sh0));
    float es1 = __expf(lrelu(a_src[(size_t)n * 4 + 1] + ad1 + eam * sh1));
    float es2 = __expf(lrelu(a_src[(size_t)n * 4 + 2] + ad2 + eam * sh2));
    float es3 = __expf(lrelu(a_src[(size_t)n * 4 + 3] + ad3 + eam * sh3));

    // phase 1: denominators
    float d0 = 0.f, d1 = 0.f, d2 = 0.f, d3 = 0.f;
    for (int p = beg + t; p < end; p += 256) {
        int e = csr[p];
        int s = edge_read(ei, is64, (size_t)e);
        float w = ew[e];
        const float* as = &a_src[(size_t)s * 4];
        d0 += __expf(lrelu(as[0] + ad0 + w * sh0));
        d1 += __expf(lrelu(as[1] + ad1 + w * sh1));
        d2 += __expf(lrelu(as[2] + ad2 + w * sh2));
        d3 += __expf(lrelu(as[3] + ad3 + w * sh3));
    }
    s_red[t] = make_float4(d0, d1, d2, d3);
    __syncthreads();
    for (int s = 128; s > 0; s >>= 1) {
        if (t < s) {
            float4 a = s_red[t], b = s_red[t + s];
            s_red[t] = make_float4(a.x + b.x, a.y + b.y, a.z + b.z, a.w + b.w);
        }
        __syncthreads();
    }
    float4 dt = s_red[0];
    float den0 = dt.x + es0 + 1e-16f, den1 = dt.y + es1 + 1e-16f;
    float den2 = dt.z + es2 + 1e-16f, den3 = dt.w + es3 + 1e-16f;

    // phase 2: gather
    int h0 = t >> 7;               // head of channel t (0 or 1)
    float es_lo  = h0 ? es1 : es0;
    float es_hi  = h0 ? es3 : es2;
    float den_lo = h0 ? den1 : den0;
    float den_hi = h0 ? den3 : den2;

    size_t nrow = (size_t)n * HC;
    float acc0 = x[nrow + t]       * es_lo;   // self loop
    float acc1 = x[nrow + 256 + t] * es_hi;

    for (int cb = beg; cb < end; cb += 256) {
        int m = end - cb; if (m > 256) m = 256;
        __syncthreads();
        if (t < m) {
            int e = csr[cb + t];
            int s = edge_read(ei, is64, (size_t)e);
            float w = ew[e];
            const float* as = &a_src[(size_t)s * 4];
            s_srcv[t] = s;
            s_alpha[t][0] = __expf(lrelu(as[0] + ad0 + w * sh0));
            s_alpha[t][1] = __expf(lrelu(as[1] + ad1 + w * sh1));
            s_alpha[t][2] = __expf(lrelu(as[2] + ad2 + w * sh2));
            s_alpha[t][3] = __expf(lrelu(as[3] + ad3 + w * sh3));
        }
        __syncthreads();
        for (int e2 = 0; e2 < m; ++e2) {
            size_t srow = (size_t)s_srcv[e2] * HC;
            float w_lo = s_alpha[e2][h0];
            float w_hi = s_alpha[e2][2 + h0];
            acc0 += x[srow + t]       * w_lo;
            acc1 += x[srow + 256 + t] * w_hi;
        }
    }
    agg[nrow + t]       = acc0 / den_lo + bias[t];
    agg[nrow + 256 + t] = acc1 / den_hi + bias[256 + t];
}

// ---------------------------------------------------------------------------
extern "C" void kernel_launch(void* const* d_in, const int* in_sizes, int n_in,
                              void* d_out, int out_size, void* d_ws, size_t ws_size,
                              hipStream_t stream) {
    const int*   edge_index  = (const int*)d_in[0];
    const float* edge_weight = (const float*)d_in[1];
    const float* emb         = (const float*)d_in[2];
    const float* W           = (const float*)d_in[3];
    const float* att_src     = (const float*)d_in[4];
    const float* att_dst     = (const float*)d_in[5];
    const float* att_edge    = (const float*)d_in[6];
    const float* W_edge      = (const float*)d_in[7];
    const float* bias        = (const float*)d_in[8];
    const float* W_out       = (const float*)d_in[9];
    const float* b_out       = (const float*)d_in[10];
    float* out = (float*)d_out;

    const int E = in_sizes[1];
    const int D = 256;
    const int N = in_sizes[2] / D;

    char* ws = (char*)d_ws;
    size_t off = 0;
    auto alloc = [&](size_t bytes) {
        size_t o = off;
        off += (bytes + 255) & ~(size_t)255;
        return o;
    };
    float* x       = (float*)(ws + alloc((size_t)N * HC * 4));
    float* agg     = (float*)(ws + alloc((size_t)N * HC * 4));
    float* a_src   = (float*)(ws + alloc((size_t)N * 4 * 4));
    float* a_dst   = (float*)(ws + alloc((size_t)N * 4 * 4));
    float* sh      = (float*)(ws + alloc(64));
    float* ea_mean = (float*)(ws + alloc((size_t)N * 4));
    size_t zoff    = alloc((size_t)N * 4 * 3);     // wsum | cnt | fill (zeroed)
    float* wsum    = (float*)(ws + zoff);
    int*   cnt     = (int*)(ws + zoff + (size_t)N * 4);
    int*   fillc   = (int*)(ws + zoff + (size_t)N * 8);
    int*   offsets = (int*)(ws + alloc((size_t)(N + 1) * 4));
    int*   csr     = (int*)(ws + alloc((size_t)E * 4));
    int*   flag    = (int*)(ws + alloc(4));
    (void)ws_size; (void)n_in; (void)out_size; (void)att_edge;

    hipMemsetAsync(ws + zoff, 0, (size_t)N * 4 * 3, stream);
    detect_kernel<<<1, 256, 0, stream>>>(edge_index, E, flag);

    // x = emb @ W  (M=N, K=256, Nc=512)
    gemm_kernel<<<dim3(HC / 64, (N + 63) / 64), 256, 0, stream>>>(
        emb, W, nullptr, x, N, D, HC);
    attdot_kernel<<<N, 256, 0, stream>>>(x, att_src, att_dst, a_src, a_dst, N);

    edge_stats_kernel<<<(E + 255) / 256, 256, 0, stream>>>(
        edge_index, edge_weight, flag, cnt, wsum, E);
    scan_kernel<<<1, 1024, 0, stream>>>(
        cnt, wsum, offsets, ea_mean, W_edge, att_edge, sh, N);
    fill_kernel<<<(E + 255) / 256, 256, 0, stream>>>(
        edge_index, flag, offsets, fillc, csr, E);

    agg_kernel<<<N, 256, 0, stream>>>(
        x, a_src, a_dst, ea_mean, sh, edge_weight, edge_index, flag,
        csr, offsets, bias, agg, N, E);

    // out = agg @ W_out + b_out  (M=N, K=512, Nc=256)
    gemm_kernel<<<dim3(D / 64, (N + 63) / 64), 256, 0, stream>>>(
        agg, W_out, b_out, out, N, HC, D);
}

// Round 2
// 396.220 us; speedup vs baseline: 2.5592x; 2.5592x over previous
//
#include <hip/hip_runtime.h>
#include <cstdint>
#include <cstddef>

#define NEG_SLOPE 0.2f
#define HC 512
#define NH 4

typedef __attribute__((ext_vector_type(8))) short bf16x8;   // 8 bf16 in 4 VGPRs
typedef __attribute__((ext_vector_type(4))) float f32x4;

__device__ inline float lrelu(float z) { return z > 0.f ? z : NEG_SLOPE * z; }

__device__ inline unsigned short f2bf(float f) {            // round-to-nearest-even
    unsigned u = __float_as_uint(f);
    u += 0x7FFFu + ((u >> 16) & 1u);
    return (unsigned short)(u >> 16);
}
__device__ inline float bf2f(unsigned short v) {
    return __uint_as_float(((unsigned)v) << 16);
}

#define GLOAD16(gp, lp) \
    __builtin_amdgcn_global_load_lds( \
        (const __attribute__((address_space(1))) unsigned int*)(const void*)(gp), \
        (__attribute__((address_space(3))) unsigned int*)(void*)(lp), 16, 0, 0)

// ---------------------------------------------------------------------------
// int64-vs-int32 edge_index layout probe
__global__ void detect_kernel(const int* __restrict__ ei, int E, int* __restrict__ flag) {
    __shared__ int nz;
    if (threadIdx.x == 0) nz = 0;
    __syncthreads();
    int lim = E < 256 ? E : 256;
    if (threadIdx.x < lim)
        if (ei[2 * threadIdx.x + 1] != 0) atomicOr(&nz, 1);
    __syncthreads();
    if (threadIdx.x == 0) *flag = (nz == 0) ? 1 : 0;        // 1 -> int64
}

__device__ inline int edge_read(const int* ei, int is64, size_t idx) {
    return is64 ? ei[2 * idx] : ei[idx];
}

// ---------------------------------------------------------------------------
// fp32 -> bf16 cast (vectorized)
__global__ __launch_bounds__(256) void cast_kernel(const float* __restrict__ src,
                                                   unsigned short* __restrict__ dst, int n4) {
    int i = blockIdx.x * 256 + threadIdx.x;
    if (i >= n4) return;
    float4 v = reinterpret_cast<const float4*>(src)[i];
    ushort4 o;
    o.x = f2bf(v.x); o.y = f2bf(v.y); o.z = f2bf(v.z); o.w = f2bf(v.w);
    reinterpret_cast<ushort4*>(dst)[i] = o;
}

// cast + transpose: src[R][C] fp32 -> dstT[C][R] bf16   (tiny weight matrices)
__global__ __launch_bounds__(256) void castT_kernel(const float* __restrict__ src,
                                                    unsigned short* __restrict__ dstT,
                                                    int R, int C) {
    int idx = blockIdx.x * 256 + threadIdx.x;
    if (idx >= R * C) return;
    int r = idx >> 31 ? 0 : idx / C;   // C is pow2 here, compiler strength-reduces
    int c = idx - r * C;
    dstT[(size_t)c * R + r] = f2bf(src[idx]);
}

// ---------------------------------------------------------------------------
// bf16 MFMA GEMM: C[M][Nc] = A[M][K] * BT[Nc][K]^T  (both operands K-contig)
// 128x128 tile, BK=32, 4 waves (each owns 64x64), 16x16x32 MFMA.
template<int K, bool BIAS, bool OUT_BF16>
__global__ __launch_bounds__(256) void gemm_bf16(
        const unsigned short* __restrict__ A,
        const unsigned short* __restrict__ BT,
        const float* __restrict__ bias,
        unsigned short* __restrict__ Cb, float* __restrict__ Cf,
        int M, int Nc) {
    __shared__ __align__(16) unsigned short As[128 * 32];
    __shared__ __align__(16) unsigned short Bs[128 * 32];
    int tid = threadIdx.x;
    int lane = tid & 63, w = tid >> 6;
    int bm = blockIdx.y * 128, bn = blockIdx.x * 128;
    int wr = w >> 1, wc = w & 1;

    f32x4 acc[4][4];
    #pragma unroll
    for (int i = 0; i < 4; ++i)
        #pragma unroll
        for (int j = 0; j < 4; ++j)
            acc[i][j] = (f32x4){0.f, 0.f, 0.f, 0.f};

    int lr = lane & 15, kb = lane >> 4;

    for (int k0 = 0; k0 < K; k0 += 32) {
        #pragma unroll
        for (int p = 0; p < 2; ++p) {
            int ob = p * 4096 + w * 1024;          // wave-uniform LDS byte base
            int o  = ob + lane * 16;               // this lane's byte slot
            int row = o >> 6;                      // 64 B per LDS row (32 bf16)
            int col = (o & 63) >> 1;
            int gr = bm + row; if (gr >= M) gr = M - 1;
            GLOAD16(A + (size_t)gr * K + k0 + col, (char*)As + ob);
            int gn = bn + row;                     // Nc multiple of 128: in-bounds
            GLOAD16(BT + (size_t)gn * K + k0 + col, (char*)Bs + ob);
        }
        __syncthreads();

        bf16x8 a[4], b[4];
        #pragma unroll
        for (int i = 0; i < 4; ++i)
            a[i] = *reinterpret_cast<const bf16x8*>(&As[(wr * 64 + i * 16 + lr) * 32 + kb * 8]);
        #pragma unroll
        for (int j = 0; j < 4; ++j)
            b[j] = *reinterpret_cast<const bf16x8*>(&Bs[(wc * 64 + j * 16 + lr) * 32 + kb * 8]);
        #pragma unroll
        for (int i = 0; i < 4; ++i)
            #pragma unroll
            for (int j = 0; j < 4; ++j)
                acc[i][j] = __builtin_amdgcn_mfma_f32_16x16x32_bf16(a[i], b[j], acc[i][j], 0, 0, 0);
        __syncthreads();
    }

    int rg = lane >> 4;
    #pragma unroll
    for (int i = 0; i < 4; ++i) {
        #pragma unroll
        for (int r = 0; r < 4; ++r) {
            int row = bm + wr * 64 + i * 16 + rg * 4 + r;
            if (row >= M) continue;
            #pragma unroll
            for (int j = 0; j < 4; ++j) {
                int col = bn + wc * 64 + j * 16 + lr;
                float v = acc[i][j][r];
                if (BIAS) v += bias[col];
                if (OUT_BF16) Cb[(size_t)row * Nc + col] = f2bf(v);
                else          Cf[(size_t)row * Nc + col] = v;
            }
        }
    }
}

// ---------------------------------------------------------------------------
// a_src[n,h], a_dst[n,h] from bf16 x. One block per node; wave w = head w.
__global__ __launch_bounds__(256) void attdot_kernel(
        const unsigned* __restrict__ xb32, const float* __restrict__ att_s,
        const float* __restrict__ att_d, float* __restrict__ a_src,
        float* __restrict__ a_dst, int N) {
    int n = blockIdx.x, t = threadIdx.x;
    unsigned v = xb32[(size_t)n * 256 + t];
    float x0 = bf2f((unsigned short)(v & 0xffff));
    float x1 = bf2f((unsigned short)(v >> 16));
    int c = 2 * t;
    float s = x0 * att_s[c] + x1 * att_s[c + 1];
    float d = x0 * att_d[c] + x1 * att_d[c + 1];
    #pragma unroll
    for (int o = 32; o > 0; o >>= 1) {
        s += __shfl_xor(s, o);
        d += __shfl_xor(d, o);
    }
    if ((t & 63) == 0) {
        a_src[(size_t)n * 4 + (t >> 6)] = s;
        a_dst[(size_t)n * 4 + (t >> 6)] = d;
    }
}

// ---------------------------------------------------------------------------
__global__ __launch_bounds__(256) void edge_stats_kernel(
        const int* __restrict__ ei, const float* __restrict__ ew,
        const int* __restrict__ flag, int* __restrict__ cnt,
        float* __restrict__ wsum, int E) {
    int e = blockIdx.x * 256 + threadIdx.x;
    if (e >= E) return;
    int is64 = *flag;
    int d = edge_read(ei, is64, (size_t)E + e);
    atomicAdd(&cnt[d], 1);
    atomicAdd(&wsum[d], ew[e]);
}

// ---------------------------------------------------------------------------
// hierarchical exclusive scan of cnt -> offsets (3 kernels)
__global__ __launch_bounds__(256) void scan1_kernel(
        const int* __restrict__ cnt, const float* __restrict__ wsum,
        int* __restrict__ offsets, int* __restrict__ bsum,
        float* __restrict__ ea_mean, int N) {
    int b = blockIdx.x, t = threadIdx.x, i = b * 256 + t;
    int v = (i < N) ? cnt[i] : 0;
    if (i < N) ea_mean[i] = wsum[i] / fmaxf((float)v, 1.f);
    int lane = t & 63, w = t >> 6;
    int s = v;
    #pragma unroll
    for (int o = 1; o < 64; o <<= 1) {
        int u = __shfl_up(s, o);
        if (lane >= o) s += u;
    }
    __shared__ int ws_[4];
    if (lane == 63) ws_[w] = s;
    __syncthreads();
    int base = 0;
    for (int k = 0; k < 4; ++k) if (k < w) base += ws_[k];
    if (i < N) offsets[i] = base + s - v;
    if (t == 0) bsum[b] = ws_[0] + ws_[1] + ws_[2] + ws_[3];
}

__global__ __launch_bounds__(256) void scan2_kernel(
        const int* __restrict__ bsum, int* __restrict__ bbase, int nb,
        int* __restrict__ offsets, int N, int E,
        const float* __restrict__ W_edge, const float* __restrict__ att_edge,
        float* __restrict__ sh) {
    int t = threadIdx.x;
    if (t < NH) {
        float s = 0.f;
        for (int c = 0; c < 128; ++c) s += W_edge[t * 128 + c] * att_edge[t * 128 + c];
        sh[t] = s;
    }
    int v = (t < nb) ? bsum[t] : 0;
    int lane = t & 63, w = t >> 6;
    int s = v;
    #pragma unroll
    for (int o = 1; o < 64; o <<= 1) {
        int u = __shfl_up(s, o);
        if (lane >= o) s += u;
    }
    __shared__ int ws_[4];
    if (lane == 63) ws_[w] = s;
    __syncthreads();
    int base = 0;
    for (int k = 0; k < 4; ++k) if (k < w) base += ws_[k];
    if (t < nb) bbase[t] = base + s - v;
    if (t == 0) offsets[N] = E;
}

__global__ __launch_bounds__(256) void scan3_kernel(
        int* __restrict__ offsets, const int* __restrict__ bbase, int N) {
    int i = blockIdx.x * 256 + threadIdx.x;
    if (i < N) offsets[i] += bbase[blockIdx.x];
}

// ---------------------------------------------------------------------------
__global__ __launch_bounds__(256) void fill_kernel(
        const int* __restrict__ ei, const int* __restrict__ flag,
        const int* __restrict__ offsets, int* __restrict__ fill,
        int* __restrict__ csr, int E) {
    int e = blockIdx.x * 256 + threadIdx.x;
    if (e >= E) return;
    int is64 = *flag;
    int d = edge_read(ei, is64, (size_t)E + e);
    int pos = offsets[d] + atomicAdd(&fill[d], 1);
    csr[pos] = e;
}

// ---------------------------------------------------------------------------
// One block per dst node. Single pass: accumulate unnormalized messages AND
// the softmax denominator, divide at the end. x gathered as bf16 (uint pairs).
// Thread t handles channels 2t, 2t+1 (head h = t>>6).
__global__ __launch_bounds__(256) void agg_kernel(
        const unsigned* __restrict__ xb32, const float* __restrict__ a_src,
        const float* __restrict__ a_dst, const float* __restrict__ ea_mean,
        const float* __restrict__ sh, const float* __restrict__ ew,
        const int* __restrict__ ei, const int* __restrict__ flag,
        const int* __restrict__ csr, const int* __restrict__ offsets,
        const float* __restrict__ bias, unsigned* __restrict__ aggb,
        int N, int E) {
    int n = blockIdx.x;
    int t = threadIdx.x;
    int is64 = *flag;
    int beg = offsets[n], end = offsets[n + 1];
    int h = t >> 6;

    __shared__ float s_alpha[256][4];
    __shared__ int   s_srcv[256];

    float ad0 = a_dst[(size_t)n * 4 + 0], ad1 = a_dst[(size_t)n * 4 + 1];
    float ad2 = a_dst[(size_t)n * 4 + 2], ad3 = a_dst[(size_t)n * 4 + 3];
    float sh0 = sh[0], sh1 = sh[1], sh2 = sh[2], sh3 = sh[3];
    float eam = ea_mean[n];
    float esh;   // self-loop alpha for my head
    {
        float adh = (h == 0) ? ad0 : (h == 1) ? ad1 : (h == 2) ? ad2 : ad3;
        float shh = (h == 0) ? sh0 : (h == 1) ? sh1 : (h == 2) ? sh2 : sh3;
        esh = __expf(lrelu(a_src[(size_t)n * 4 + h] + adh + eam * shh));
    }

    size_t nrow = (size_t)n * 256;
    unsigned v = xb32[nrow + t];
    float acc0 = bf2f((unsigned short)(v & 0xffff)) * esh;
    float acc1 = bf2f((unsigned short)(v >> 16)) * esh;
    float den = esh;

    for (int cb = beg; cb < end; cb += 256) {
        int m = end - cb; if (m > 256) m = 256;
        __syncthreads();
        if (t < m) {
            int e = csr[cb + t];
            int s = edge_read(ei, is64, (size_t)e);
            float wgt = ew[e];
            const float* as = &a_src[(size_t)s * 4];
            s_srcv[t] = s;
            s_alpha[t][0] = __expf(lrelu(as[0] + ad0 + wgt * sh0));
            s_alpha[t][1] = __expf(lrelu(as[1] + ad1 + wgt * sh1));
            s_alpha[t][2] = __expf(lrelu(as[2] + ad2 + wgt * sh2));
            s_alpha[t][3] = __expf(lrelu(as[3] + ad3 + wgt * sh3));
        }
        __syncthreads();
        for (int e2 = 0; e2 < m; ++e2) {
            float wh = s_alpha[e2][h];
            unsigned vv = xb32[(size_t)s_srcv[e2] * 256 + t];
            acc0 += wh * bf2f((unsigned short)(vv & 0xffff));
            acc1 += wh * bf2f((unsigned short)(vv >> 16));
            den += wh;
        }
    }
    float inv = 1.f / (den + 1e-16f);
    float o0 = acc0 * inv + bias[2 * t];
    float o1 = acc1 * inv + bias[2 * t + 1];
    aggb[nrow + t] = (unsigned)f2bf(o0) | ((unsigned)f2bf(o1) << 16);
}

// ---------------------------------------------------------------------------
extern "C" void kernel_launch(void* const* d_in, const int* in_sizes, int n_in,
                              void* d_out, int out_size, void* d_ws, size_t ws_size,
                              hipStream_t stream) {
    const int*   edge_index  = (const int*)d_in[0];
    const float* edge_weight = (const float*)d_in[1];
    const float* emb         = (const float*)d_in[2];
    const float* W           = (const float*)d_in[3];
    const float* att_src     = (const float*)d_in[4];
    const float* att_dst     = (const float*)d_in[5];
    const float* att_edge    = (const float*)d_in[6];
    const float* W_edge      = (const float*)d_in[7];
    const float* bias        = (const float*)d_in[8];
    const float* W_out       = (const float*)d_in[9];
    const float* b_out       = (const float*)d_in[10];
    float* out = (float*)d_out;

    const int E = in_sizes[1];
    const int D = 256;
    const int N = in_sizes[2] / D;
    const int nb = (N + 255) / 256;

    char* ws = (char*)d_ws;
    size_t off = 0;
    auto alloc = [&](size_t bytes) {
        size_t o = off;
        off += (bytes + 255) & ~(size_t)255;
        return o;
    };
    unsigned short* embb  = (unsigned short*)(ws + alloc((size_t)N * D * 2));
    unsigned short* xb    = (unsigned short*)(ws + alloc((size_t)N * HC * 2));
    unsigned short* aggb  = (unsigned short*)(ws + alloc((size_t)N * HC * 2));
    unsigned short* WT    = (unsigned short*)(ws + alloc((size_t)D * HC * 2));
    unsigned short* WoT   = (unsigned short*)(ws + alloc((size_t)HC * D * 2));
    float* a_src   = (float*)(ws + alloc((size_t)N * 4 * 4));
    float* a_dst   = (float*)(ws + alloc((size_t)N * 4 * 4));
    float* sh      = (float*)(ws + alloc(64));
    float* ea_mean = (float*)(ws + alloc((size_t)N * 4));
    size_t zoff    = alloc((size_t)N * 4 * 3);     // wsum | cnt | fill (zeroed)
    float* wsum    = (float*)(ws + zoff);
    int*   cnt     = (int*)(ws + zoff + (size_t)N * 4);
    int*   fillc   = (int*)(ws + zoff + (size_t)N * 8);
    int*   offsets = (int*)(ws + alloc((size_t)(N + 1) * 4));
    int*   csr     = (int*)(ws + alloc((size_t)E * 4));
    int*   bsum    = (int*)(ws + alloc((size_t)nb * 4));
    int*   bbase   = (int*)(ws + alloc((size_t)nb * 4));
    int*   flag    = (int*)(ws + alloc(4));
    (void)ws_size; (void)n_in; (void)out_size;

    hipMemsetAsync(ws + zoff, 0, (size_t)N * 4 * 3, stream);
    detect_kernel<<<1, 256, 0, stream>>>(edge_index, E, flag);

    // casts / transposes
    cast_kernel<<<((N * D / 4) + 255) / 256, 256, 0, stream>>>(emb, embb, N * D / 4);
    castT_kernel<<<(D * HC + 255) / 256, 256, 0, stream>>>(W, WT, D, HC);      // WT[512][256]
    castT_kernel<<<(HC * D + 255) / 256, 256, 0, stream>>>(W_out, WoT, HC, D); // WoT[256][512]

    // x = emb @ W   (bf16 MFMA, out bf16)
    gemm_bf16<256, false, true><<<dim3(HC / 128, (N + 127) / 128), 256, 0, stream>>>(
        embb, WT, nullptr, xb, nullptr, N, HC);

    attdot_kernel<<<N, 256, 0, stream>>>((const unsigned*)xb, att_src, att_dst,
                                         a_src, a_dst, N);

    edge_stats_kernel<<<(E + 255) / 256, 256, 0, stream>>>(
        edge_index, edge_weight, flag, cnt, wsum, E);
    scan1_kernel<<<nb, 256, 0, stream>>>(cnt, wsum, offsets, bsum, ea_mean, N);
    scan2_kernel<<<1, 256, 0, stream>>>(bsum, bbase, nb, offsets, N, E,
                                        W_edge, att_edge, sh);
    scan3_kernel<<<nb, 256, 0, stream>>>(offsets, bbase, N);
    fill_kernel<<<(E + 255) / 256, 256, 0, stream>>>(
        edge_index, flag, offsets, fillc, csr, E);

    agg_kernel<<<N, 256, 0, stream>>>(
        (const unsigned*)xb, a_src, a_dst, ea_mean, sh, edge_weight, edge_index,
        flag, csr, offsets, bias, (unsigned*)aggb, N, E);

    // out = agg @ W_out + b_out   (bf16 MFMA, out fp32)
    gemm_bf16<512, true, false><<<dim3(D / 128, (N + 127) / 128), 256, 0, stream>>>(
        aggb, WoT, b_out, nullptr, out, N, D);
}

// Round 3
// 390.566 us; speedup vs baseline: 2.5962x; 1.0145x over previous
//
#include <hip/hip_runtime.h>
#include <cstdint>
#include <cstddef>

#define NEG_SLOPE 0.2f
#define HC 512
#define NH 4

typedef __attribute__((ext_vector_type(8))) short bf16x8;
typedef __attribute__((ext_vector_type(4))) float f32x4;

__device__ inline float lrelu(float z) { return z > 0.f ? z : NEG_SLOPE * z; }

__device__ inline unsigned short f2bf(float f) {            // RNE
    unsigned u = __float_as_uint(f);
    u += 0x7FFFu + ((u >> 16) & 1u);
    return (unsigned short)(u >> 16);
}
__device__ inline float bf2f(unsigned short v) {
    return __uint_as_float(((unsigned)v) << 16);
}
__device__ inline float bflo(unsigned v) { return __uint_as_float(v << 16); }
__device__ inline float bfhi(unsigned v) { return __uint_as_float(v & 0xffff0000u); }

#define GLOAD16(gp, lp) \
    __builtin_amdgcn_global_load_lds( \
        (const __attribute__((address_space(1))) unsigned int*)(const void*)(gp), \
        (__attribute__((address_space(3))) unsigned int*)(void*)(lp), 16, 0, 0)

// ---------------------------------------------------------------------------
__global__ void detect_kernel(const int* __restrict__ ei, int E, int* __restrict__ flag) {
    __shared__ int nz;
    if (threadIdx.x == 0) nz = 0;
    __syncthreads();
    int lim = E < 256 ? E : 256;
    if (threadIdx.x < lim)
        if (ei[2 * threadIdx.x + 1] != 0) atomicOr(&nz, 1);
    __syncthreads();
    if (threadIdx.x == 0) *flag = (nz == 0) ? 1 : 0;        // 1 -> int64
}

__device__ inline int edge_read(const int* ei, int is64, size_t idx) {
    return is64 ? ei[2 * idx] : ei[idx];
}

// ---------------------------------------------------------------------------
__global__ __launch_bounds__(256) void cast_kernel(const float* __restrict__ src,
                                                   unsigned short* __restrict__ dst, int n4) {
    int i = blockIdx.x * 256 + threadIdx.x;
    if (i >= n4) return;
    float4 v = reinterpret_cast<const float4*>(src)[i];
    ushort4 o;
    o.x = f2bf(v.x); o.y = f2bf(v.y); o.z = f2bf(v.z); o.w = f2bf(v.w);
    reinterpret_cast<ushort4*>(dst)[i] = o;
}

__global__ __launch_bounds__(256) void castT_kernel(const float* __restrict__ src,
                                                    unsigned short* __restrict__ dstT,
                                                    int R, int C) {
    int idx = blockIdx.x * 256 + threadIdx.x;
    if (idx >= R * C) return;
    int r = idx / C;
    int c = idx - r * C;
    dstT[(size_t)c * R + r] = f2bf(src[idx]);
}

// ---------------------------------------------------------------------------
// bf16 MFMA GEMM: C[M][Nc] = A[M][K] * BT[Nc][K]^T.
// 128x128 tile, BK=64, 4 waves (64x64 each), 16x16x32 MFMA.
// LDS rows are 128 B (32 banks); 16B-column XOR-swizzled by (row&7) on BOTH
// the global source (pre-swizzle; global_load_lds dest is linear) and the
// ds_read side -> 2-way conflicts only.
template<int K, bool BIAS, bool OUT_BF16>
__global__ __launch_bounds__(256) void gemm_bf16(
        const unsigned short* __restrict__ A,
        const unsigned short* __restrict__ BT,
        const float* __restrict__ bias,
        unsigned short* __restrict__ Cb, float* __restrict__ Cf,
        int M, int Nc) {
    __shared__ __align__(16) unsigned short As[128 * 64];
    __shared__ __align__(16) unsigned short Bs[128 * 64];
    int tid = threadIdx.x;
    int lane = tid & 63, w = tid >> 6;
    int bm = blockIdx.y * 128, bn = blockIdx.x * 128;
    int wr = w >> 1, wc = w & 1;

    f32x4 acc[4][4];
    #pragma unroll
    for (int i = 0; i < 4; ++i)
        #pragma unroll
        for (int j = 0; j < 4; ++j)
            acc[i][j] = (f32x4){0.f, 0.f, 0.f, 0.f};

    int lr = lane & 15, kb = lane >> 4;
    int q = lane & 7;                      // 16B-quarter within a 128 B row

    for (int k0 = 0; k0 < K; k0 += 64) {
        #pragma unroll
        for (int p = 0; p < 4; ++p) {
            int row = p * 32 + w * 8 + (lane >> 3);     // dest row in tile
            int ce  = ((q ^ (row & 7)) << 3) + k0;      // pre-swizzled src col
            int ob  = p * 4096 + w * 1024;              // wave-uniform LDS base
            int gr = bm + row; if (gr >= M) gr = M - 1;
            GLOAD16(A + (size_t)gr * K + ce, (char*)As + ob);
            int gn = bn + row;                          // Nc % 128 == 0
            GLOAD16(BT + (size_t)gn * K + ce, (char*)Bs + ob);
        }
        __syncthreads();

        #pragma unroll
        for (int kk = 0; kk < 2; ++kk) {
            bf16x8 a[4], b[4];
            #pragma unroll
            for (int i = 0; i < 4; ++i) {
                int row = wr * 64 + i * 16 + lr;
                a[i] = *reinterpret_cast<const bf16x8*>(
                    &As[row * 64 + (((kk * 4 + kb) ^ (row & 7)) << 3)]);
            }
            #pragma unroll
            for (int j = 0; j < 4; ++j) {
                int row = wc * 64 + j * 16 + lr;
                b[j] = *reinterpret_cast<const bf16x8*>(
                    &Bs[row * 64 + (((kk * 4 + kb) ^ (row & 7)) << 3)]);
            }
            #pragma unroll
            for (int i = 0; i < 4; ++i)
                #pragma unroll
                for (int j = 0; j < 4; ++j)
                    acc[i][j] = __builtin_amdgcn_mfma_f32_16x16x32_bf16(a[i], b[j], acc[i][j], 0, 0, 0);
        }
        __syncthreads();
    }

    int rg = lane >> 4;
    #pragma unroll
    for (int i = 0; i < 4; ++i) {
        #pragma unroll
        for (int r = 0; r < 4; ++r) {
            int row = bm + wr * 64 + i * 16 + rg * 4 + r;
            if (row >= M) continue;
            #pragma unroll
            for (int j = 0; j < 4; ++j) {
                int col = bn + wc * 64 + j * 16 + lr;
                float v = acc[i][j][r];
                if (BIAS) v += bias[col];
                if (OUT_BF16) Cb[(size_t)row * Nc + col] = f2bf(v);
                else          Cf[(size_t)row * Nc + col] = v;
            }
        }
    }
}

// ---------------------------------------------------------------------------
__global__ __launch_bounds__(256) void attdot_kernel(
        const unsigned* __restrict__ xb32, const float* __restrict__ att_s,
        const float* __restrict__ att_d, float* __restrict__ a_src,
        float* __restrict__ a_dst, int N) {
    int n = blockIdx.x, t = threadIdx.x;
    unsigned v = xb32[(size_t)n * 256 + t];
    float x0 = bflo(v), x1 = bfhi(v);
    int c = 2 * t;
    float s = x0 * att_s[c] + x1 * att_s[c + 1];
    float d = x0 * att_d[c] + x1 * att_d[c + 1];
    #pragma unroll
    for (int o = 32; o > 0; o >>= 1) {
        s += __shfl_xor(s, o);
        d += __shfl_xor(d, o);
    }
    if ((t & 63) == 0) {
        a_src[(size_t)n * 4 + (t >> 6)] = s;
        a_dst[(size_t)n * 4 + (t >> 6)] = d;
    }
}

// ---------------------------------------------------------------------------
__global__ __launch_bounds__(256) void edge_stats_kernel(
        const int* __restrict__ ei, const float* __restrict__ ew,
        const int* __restrict__ flag, int* __restrict__ cnt,
        float* __restrict__ wsum, int E) {
    int e = blockIdx.x * 256 + threadIdx.x;
    if (e >= E) return;
    int is64 = *flag;
    int d = edge_read(ei, is64, (size_t)E + e);
    atomicAdd(&cnt[d], 1);
    atomicAdd(&wsum[d], ew[e]);
}

// ---------------------------------------------------------------------------
__global__ __launch_bounds__(256) void scan1_kernel(
        const int* __restrict__ cnt, const float* __restrict__ wsum,
        int* __restrict__ offsets, int* __restrict__ bsum,
        float* __restrict__ ea_mean, int N) {
    int b = blockIdx.x, t = threadIdx.x, i = b * 256 + t;
    int v = (i < N) ? cnt[i] : 0;
    if (i < N) ea_mean[i] = wsum[i] / fmaxf((float)v, 1.f);
    int lane = t & 63, w = t >> 6;
    int s = v;
    #pragma unroll
    for (int o = 1; o < 64; o <<= 1) {
        int u = __shfl_up(s, o);
        if (lane >= o) s += u;
    }
    __shared__ int ws_[4];
    if (lane == 63) ws_[w] = s;
    __syncthreads();
    int base = 0;
    for (int k = 0; k < 4; ++k) if (k < w) base += ws_[k];
    if (i < N) offsets[i] = base + s - v;
    if (t == 0) bsum[b] = ws_[0] + ws_[1] + ws_[2] + ws_[3];
}

__global__ __launch_bounds__(256) void scan2_kernel(
        const int* __restrict__ bsum, int* __restrict__ bbase, int nb,
        int* __restrict__ offsets, int N, int E,
        const float* __restrict__ W_edge, const float* __restrict__ att_edge,
        float* __restrict__ sh) {
    int t = threadIdx.x;
    if (t < NH) {
        float s = 0.f;
        for (int c = 0; c < 128; ++c) s += W_edge[t * 128 + c] * att_edge[t * 128 + c];
        sh[t] = s;
    }
    int v = (t < nb) ? bsum[t] : 0;
    int lane = t & 63, w = t >> 6;
    int s = v;
    #pragma unroll
    for (int o = 1; o < 64; o <<= 1) {
        int u = __shfl_up(s, o);
        if (lane >= o) s += u;
    }
    __shared__ int ws_[4];
    if (lane == 63) ws_[w] = s;
    __syncthreads();
    int base = 0;
    for (int k = 0; k < 4; ++k) if (k < w) base += ws_[k];
    if (t < nb) bbase[t] = base + s - v;
    if (t == 0) offsets[N] = E;
}

__global__ __launch_bounds__(256) void scan3_kernel(
        int* __restrict__ offsets, const int* __restrict__ bbase, int N) {
    int i = blockIdx.x * 256 + threadIdx.x;
    if (i < N) offsets[i] += bbase[blockIdx.x];
}

// ---------------------------------------------------------------------------
__global__ __launch_bounds__(256) void fill_kernel(
        const int* __restrict__ ei, const int* __restrict__ flag,
        const int* __restrict__ offsets, int* __restrict__ fill,
        int* __restrict__ csr, int E) {
    int e = blockIdx.x * 256 + threadIdx.x;
    if (e >= E) return;
    int is64 = *flag;
    int d = edge_read(ei, is64, (size_t)E + e);
    int pos = offsets[d] + atomicAdd(&fill[d], 1);
    csr[pos] = e;
}

// ---------------------------------------------------------------------------
// One WAVE per dst node; lane owns 8 channels (uint4). One dwordx4 wave-instr
// per edge row. Per-wave LDS alpha slices (wave-ordered DS => no barriers).
__global__ __launch_bounds__(256) void agg_kernel(
        const uint4* __restrict__ xq, const float* __restrict__ a_src,
        const float* __restrict__ a_dst, const float* __restrict__ ea_mean,
        const float* __restrict__ sh, const float* __restrict__ ew,
        const int* __restrict__ ei, const int* __restrict__ flag,
        const int* __restrict__ csr, const int* __restrict__ offsets,
        const float* __restrict__ bias, uint4* __restrict__ aggq,
        int N, int E) {
    int wid = threadIdx.x >> 6, lane = threadIdx.x & 63;
    int n = blockIdx.x * 4 + wid;
    if (n >= N) return;
    int is64 = *flag;
    int h = lane >> 4;                     // head of this lane's 8 channels
    int beg = offsets[n], end = offsets[n + 1];

    __shared__ float s_alpha[4][64][4];
    __shared__ int   s_src[4][64];

    float ad0 = a_dst[(size_t)n * 4 + 0], ad1 = a_dst[(size_t)n * 4 + 1];
    float ad2 = a_dst[(size_t)n * 4 + 2], ad3 = a_dst[(size_t)n * 4 + 3];
    float sh0 = sh[0], sh1 = sh[1], sh2 = sh[2], sh3 = sh[3];
    float eam = ea_mean[n];
    float adh = (h == 0) ? ad0 : (h == 1) ? ad1 : (h == 2) ? ad2 : ad3;
    float shh = (h == 0) ? sh0 : (h == 1) ? sh1 : (h == 2) ? sh2 : sh3;
    float es = __expf(lrelu(a_src[(size_t)n * 4 + h] + adh + eam * shh));

    uint4 xv = xq[(size_t)n * 64 + lane];  // self loop
    float a0 = es * bflo(xv.x), a1 = es * bfhi(xv.x);
    float a2 = es * bflo(xv.y), a3 = es * bfhi(xv.y);
    float a4 = es * bflo(xv.z), a5 = es * bfhi(xv.z);
    float a6 = es * bflo(xv.w), a7 = es * bfhi(xv.w);
    float den = es;

    for (int cb = beg; cb < end; cb += 64) {
        int m = end - cb; if (m > 64) m = 64;
        if (lane < m) {
            int e = csr[cb + lane];
            int s = edge_read(ei, is64, (size_t)e);
            float wgt = ew[e];
            s_src[wid][lane] = s;
            const float* as = &a_src[(size_t)s * 4];
            s_alpha[wid][lane][0] = __expf(lrelu(as[0] + ad0 + wgt * sh0));
            s_alpha[wid][lane][1] = __expf(lrelu(as[1] + ad1 + wgt * sh1));
            s_alpha[wid][lane][2] = __expf(lrelu(as[2] + ad2 + wgt * sh2));
            s_alpha[wid][lane][3] = __expf(lrelu(as[3] + ad3 + wgt * sh3));
        }
        // same-wave DS ops are in order; lgkmcnt wait is compiler-inserted.
        int e2 = 0;
        for (; e2 + 2 <= m; e2 += 2) {
            int   s0 = s_src[wid][e2],     s1 = s_src[wid][e2 + 1];
            float w0 = s_alpha[wid][e2][h], w1 = s_alpha[wid][e2 + 1][h];
            uint4 v0 = xq[(size_t)s0 * 64 + lane];
            uint4 v1 = xq[(size_t)s1 * 64 + lane];
            a0 += w0 * bflo(v0.x) + w1 * bflo(v1.x);
            a1 += w0 * bfhi(v0.x) + w1 * bfhi(v1.x);
            a2 += w0 * bflo(v0.y) + w1 * bflo(v1.y);
            a3 += w0 * bfhi(v0.y) + w1 * bfhi(v1.y);
            a4 += w0 * bflo(v0.z) + w1 * bflo(v1.z);
            a5 += w0 * bfhi(v0.z) + w1 * bfhi(v1.z);
            a6 += w0 * bflo(v0.w) + w1 * bflo(v1.w);
            a7 += w0 * bfhi(v0.w) + w1 * bfhi(v1.w);
            den += w0 + w1;
        }
        if (e2 < m) {
            int   s0 = s_src[wid][e2];
            float w0 = s_alpha[wid][e2][h];
            uint4 v0 = xq[(size_t)s0 * 64 + lane];
            a0 += w0 * bflo(v0.x);  a1 += w0 * bfhi(v0.x);
            a2 += w0 * bflo(v0.y);  a3 += w0 * bfhi(v0.y);
            a4 += w0 * bflo(v0.z);  a5 += w0 * bfhi(v0.z);
            a6 += w0 * bflo(v0.w);  a7 += w0 * bfhi(v0.w);
            den += w0;
        }
    }

    float inv = 1.f / (den + 1e-16f);
    float4 b0 = reinterpret_cast<const float4*>(bias)[lane * 2];
    float4 b1 = reinterpret_cast<const float4*>(bias)[lane * 2 + 1];
    uint4 o;
    o.x = (unsigned)f2bf(a0 * inv + b0.x) | ((unsigned)f2bf(a1 * inv + b0.y) << 16);
    o.y = (unsigned)f2bf(a2 * inv + b0.z) | ((unsigned)f2bf(a3 * inv + b0.w) << 16);
    o.z = (unsigned)f2bf(a4 * inv + b1.x) | ((unsigned)f2bf(a5 * inv + b1.y) << 16);
    o.w = (unsigned)f2bf(a6 * inv + b1.z) | ((unsigned)f2bf(a7 * inv + b1.w) << 16);
    aggq[(size_t)n * 64 + lane] = o;
}

// ---------------------------------------------------------------------------
extern "C" void kernel_launch(void* const* d_in, const int* in_sizes, int n_in,
                              void* d_out, int out_size, void* d_ws, size_t ws_size,
                              hipStream_t stream) {
    const int*   edge_index  = (const int*)d_in[0];
    const float* edge_weight = (const float*)d_in[1];
    const float* emb         = (const float*)d_in[2];
    const float* W           = (const float*)d_in[3];
    const float* att_src     = (const float*)d_in[4];
    const float* att_dst     = (const float*)d_in[5];
    const float* att_edge    = (const float*)d_in[6];
    const float* W_edge      = (const float*)d_in[7];
    const float* bias        = (const float*)d_in[8];
    const float* W_out       = (const float*)d_in[9];
    const float* b_out       = (const float*)d_in[10];
    float* out = (float*)d_out;

    const int E = in_sizes[1];
    const int D = 256;
    const int N = in_sizes[2] / D;
    const int nb = (N + 255) / 256;

    char* ws = (char*)d_ws;
    size_t off = 0;
    auto alloc = [&](size_t bytes) {
        size_t o = off;
        off += (bytes + 255) & ~(size_t)255;
        return o;
    };
    unsigned short* embb  = (unsigned short*)(ws + alloc((size_t)N * D * 2));
    unsigned short* xb    = (unsigned short*)(ws + alloc((size_t)N * HC * 2));
    unsigned short* aggb  = (unsigned short*)(ws + alloc((size_t)N * HC * 2));
    unsigned short* WT    = (unsigned short*)(ws + alloc((size_t)D * HC * 2));
    unsigned short* WoT   = (unsigned short*)(ws + alloc((size_t)HC * D * 2));
    float* a_src   = (float*)(ws + alloc((size_t)N * 4 * 4));
    float* a_dst   = (float*)(ws + alloc((size_t)N * 4 * 4));
    float* sh      = (float*)(ws + alloc(64));
    float* ea_mean = (float*)(ws + alloc((size_t)N * 4));
    size_t zoff    = alloc((size_t)N * 4 * 3);     // wsum | cnt | fill (zeroed)
    float* wsum    = (float*)(ws + zoff);
    int*   cnt     = (int*)(ws + zoff + (size_t)N * 4);
    int*   fillc   = (int*)(ws + zoff + (size_t)N * 8);
    int*   offsets = (int*)(ws + alloc((size_t)(N + 1) * 4));
    int*   csr     = (int*)(ws + alloc((size_t)E * 4));
    int*   bsum    = (int*)(ws + alloc((size_t)nb * 4));
    int*   bbase   = (int*)(ws + alloc((size_t)nb * 4));
    int*   flag    = (int*)(ws + alloc(4));
    (void)ws_size; (void)n_in; (void)out_size;

    hipMemsetAsync(ws + zoff, 0, (size_t)N * 4 * 3, stream);
    detect_kernel<<<1, 256, 0, stream>>>(edge_index, E, flag);

    cast_kernel<<<((N * D / 4) + 255) / 256, 256, 0, stream>>>(emb, embb, N * D / 4);
    castT_kernel<<<(D * HC + 255) / 256, 256, 0, stream>>>(W, WT, D, HC);
    castT_kernel<<<(HC * D + 255) / 256, 256, 0, stream>>>(W_out, WoT, HC, D);

    // x = emb @ W
    gemm_bf16<256, false, true><<<dim3(HC / 128, (N + 127) / 128), 256, 0, stream>>>(
        embb, WT, nullptr, xb, nullptr, N, HC);

    attdot_kernel<<<N, 256, 0, stream>>>((const unsigned*)xb, att_src, att_dst,
                                         a_src, a_dst, N);

    edge_stats_kernel<<<(E + 255) / 256, 256, 0, stream>>>(
        edge_index, edge_weight, flag, cnt, wsum, E);
    scan1_kernel<<<nb, 256, 0, stream>>>(cnt, wsum, offsets, bsum, ea_mean, N);
    scan2_kernel<<<1, 256, 0, stream>>>(bsum, bbase, nb, offsets, N, E,
                                        W_edge, att_edge, sh);
    scan3_kernel<<<nb, 256, 0, stream>>>(offsets, bbase, N);
    fill_kernel<<<(E + 255) / 256, 256, 0, stream>>>(
        edge_index, flag, offsets, fillc, csr, E);

    agg_kernel<<<(N + 3) / 4, 256, 0, stream>>>(
        (const uint4*)xb, a_src, a_dst, ea_mean, sh, edge_weight, edge_index,
        flag, csr, offsets, bias, (uint4*)aggb, N, E);

    // out = agg @ W_out + b_out
    gemm_bf16<512, true, false><<<dim3(D / 128, (N + 127) / 128), 256, 0, stream>>>(
        aggb, WoT, b_out, nullptr, out, N, D);
}